// Round 10
// baseline (90.438 us; speedup 1.0000x reference)
//
#include <hip/hip_runtime.h>
#include <cstdint>
#include <cstddef>

#define BB   32768
#define DD   8
#define LLV  16
#define TBL  524288
#define HID  512

typedef __attribute__((ext_vector_type(8))) short short8;
typedef __attribute__((ext_vector_type(8))) unsigned short u16x8;
typedef __attribute__((ext_vector_type(4))) float f32x4;
typedef __attribute__((ext_vector_type(2))) float f32x2;

// primes mod 2^32
__device__ __constant__ uint32_t PR[8] = {
    2654436881u, 1620619981u, 1500450271u, 3267000013u,
    1459886047u, 4093082899u,  986956175u, 3628273133u
};

__device__ __forceinline__ unsigned short f2bf(float f) {
    uint32_t u = __float_as_uint(f);
    uint32_t r = (u + 0x7fffu + ((u >> 16) & 1u)) >> 16;   // RNE
    return (unsigned short)r;
}

__device__ __forceinline__ void gload_lds16(const void* gsrc, void* ldst) {
    __builtin_amdgcn_global_load_lds(
        (const __attribute__((address_space(1))) unsigned int*)gsrc,
        (__attribute__((address_space(3))) unsigned int*)ldst,
        16, 0, 0);
}

// per-sample: cumsum -> sort -> 9 vertex hashes + weights
__device__ __forceinline__ void enc_idx(const float xs[8], float Kl,
                                        uint32_t idx9[9], float w9[9])
{
    float fr[8];
    int   base[8];
    float cs = 0.f;
#pragma unroll
    for (int i2 = 0; i2 < 8; i2++) {
        cs += xs[i2];                 // sequential fp32 cumsum (matches np)
        float p = cs * Kl;
        fr[i2]   = p - truncf(p);
        base[i2] = (int)floorf(p);
    }

    float c[8];
#pragma unroll
    for (int i2 = 0; i2 < 8; i2++) c[i2] = fr[i2];
#define CE(a_, b_) { float lo_ = fminf(c[a_], c[b_]); float hi_ = fmaxf(c[a_], c[b_]); c[a_] = lo_; c[b_] = hi_; }
    CE(0,1) CE(2,3) CE(4,5) CE(6,7)
    CE(0,2) CE(1,3) CE(4,6) CE(5,7)
    CE(1,2) CE(5,6) CE(0,4) CE(3,7)
    CE(1,5) CE(2,6)
    CE(1,4) CE(3,6)
    CE(2,4) CE(3,5)
    CE(3,4)
#undef CE

    float prevc = 0.f;
#pragma unroll
    for (int j = 0; j < 9; j++) {
        float cj = (j < 8) ? c[j] : 1.0f;
        uint32_t h = 0;
        int prev = 0;
#pragma unroll
        for (int i2 = 0; i2 < 8; i2++) {
            int ai = base[i2] + (fr[i2] >= cj ? 1 : 0);
            h ^= (uint32_t)(ai - prev) * PR[i2];
            prev = ai;
        }
        idx9[j] = h & (TBL - 1);
        w9[j]   = cj - prevc;
        prevc   = cj;
    }
}

// ---------------- encoding: level-major, asm-batched gathers ----------------
__global__ __launch_bounds__(256) void k_encode(
    const float* __restrict__ x, const float* __restrict__ T,
    const float* __restrict__ Karr, unsigned short* __restrict__ h0T)
{
    int i = blockIdx.x;
    int l = (i & 7) + ((i >> 10) << 3);
    int b = ((i & 1023) >> 3) * 256 + threadIdx.x;

    const float4 x0 = *(const float4*)(x + (size_t)b * DD);
    const float4 x1 = *(const float4*)(x + (size_t)b * DD + 4);
    float xs[8] = {x0.x, x0.y, x0.z, x0.w, x1.x, x1.y, x1.z, x1.w};

    float Kl = Karr[l];
    const f32x2* Tl = (const f32x2*)(T + ((size_t)l * TBL) * 2);

    uint32_t idx9[9];
    float    w9[9];
    enc_idx(xs, Kl, idx9, w9);

    f32x2 t0, t1, t2, t3, t4, t5, t6, t7, t8;
#define GL(n) asm volatile("global_load_dwordx2 %0, %1, off" \
                           : "=v"(t##n) : "v"(Tl + idx9[n]));
    GL(0) GL(1) GL(2) GL(3) GL(4) GL(5) GL(6) GL(7) GL(8)
#undef GL
    asm volatile("s_waitcnt vmcnt(0)"
        : "+v"(t0), "+v"(t1), "+v"(t2), "+v"(t3), "+v"(t4),
          "+v"(t5), "+v"(t6), "+v"(t7), "+v"(t8));
    __builtin_amdgcn_sched_barrier(0);

    float f0, f1;
    f0 = t0[0] * w9[0];  f1 = t0[1] * w9[0];
    f0 = fmaf(t1[0], w9[1], f0); f1 = fmaf(t1[1], w9[1], f1);
    f0 = fmaf(t2[0], w9[2], f0); f1 = fmaf(t2[1], w9[2], f1);
    f0 = fmaf(t3[0], w9[3], f0); f1 = fmaf(t3[1], w9[3], f1);
    f0 = fmaf(t4[0], w9[4], f0); f1 = fmaf(t4[1], w9[4], f1);
    f0 = fmaf(t5[0], w9[5], f0); f1 = fmaf(t5[1], w9[5], f1);
    f0 = fmaf(t6[0], w9[6], f0); f1 = fmaf(t6[1], w9[6], f1);
    f0 = fmaf(t7[0], w9[7], f0); f1 = fmaf(t7[1], w9[7], f1);
    f0 = fmaf(t8[0], w9[8], f0); f1 = fmaf(t8[1], w9[8], f1);
    f0 /= Kl;
    f1 /= Kl;

    h0T[(size_t)(l * 2 + 0) * BB + b] = f2bf(f0);
    h0T[(size_t)(l * 2 + 1) * BB + b] = f2bf(f1);
}

// ---------------- pack: planes + x -> row-major bf16 [B][64] (zero-padded K) ----
__global__ __launch_bounds__(256) void k_pack(
    const unsigned short* __restrict__ h0T, const float* __restrict__ x,
    unsigned short* __restrict__ h0b)
{
    int b = blockIdx.x * 256 + threadIdx.x;
    unsigned short row[64];
    const float4 x0 = *(const float4*)(x + (size_t)b * 8);
    const float4 x1 = *(const float4*)(x + (size_t)b * 8 + 4);
    row[0] = f2bf(x0.x); row[1] = f2bf(x0.y); row[2] = f2bf(x0.z); row[3] = f2bf(x0.w);
    row[4] = f2bf(x1.x); row[5] = f2bf(x1.y); row[6] = f2bf(x1.z); row[7] = f2bf(x1.w);
#pragma unroll
    for (int p = 0; p < 32; p++) row[8 + p] = h0T[(size_t)p * BB + b];
#pragma unroll
    for (int c = 40; c < 64; c++) row[c] = 0;
#pragma unroll
    for (int i = 0; i < 8; i++)
        *(u16x8*)(h0b + (size_t)b * 64 + i * 8) = *(u16x8*)(row + i * 8);
}

// ---------------- fused weight converts: w2 (256 blocks) + w1-pad (32 blocks) ----
__global__ __launch_bounds__(256) void k_cvtw(
    const float* __restrict__ w2, unsigned short* __restrict__ o2,
    const float* __restrict__ w1, unsigned short* __restrict__ o1)
{
    int bid = blockIdx.x;
    if (bid < 256) {
        int i = bid * 256 + threadIdx.x;
        float4 v = *(const float4*)(w2 + (size_t)i * 4);
        ushort4 r;
        r.x = f2bf(v.x); r.y = f2bf(v.y); r.z = f2bf(v.z); r.w = f2bf(v.w);
        *(ushort4*)(o2 + (size_t)i * 4) = r;
    } else {
        int i = (bid - 256) * 256 + threadIdx.x;   // 8192 threads
        int row = i >> 4, c4 = (i & 15) * 4;
        ushort4 r = make_ushort4(0, 0, 0, 0);
        if (c4 < 40) {
            float4 v = *(const float4*)(w1 + (size_t)row * 40 + c4);
            r.x = f2bf(v.x); r.y = f2bf(v.y); r.z = f2bf(v.z); r.w = f2bf(v.w);
        }
        *(ushort4*)(o1 + (size_t)row * 64 + c4) = r;
    }
}

// ---------------- fused MLP: 64 samples/block, 8 waves (1x8), h1 in 64KB LDS ----------------
// 512 blocks -> 2 blocks/CU (72 KB LDS) -> 4 waves/SIMD. Wave wid owns cols
// [64*wid, 64*wid+64) for ALL 64 rows: no redundant w2 reads within a block.
// Phase-2: register-dbuf prefetch (next kc's af/bfr issued before current MFMAs).
__global__ __launch_bounds__(512) void k_fused(
    const unsigned short* __restrict__ h0b, const unsigned short* __restrict__ w1b,
    const unsigned short* __restrict__ w2b, const float* __restrict__ b1,
    const float* __restrict__ b2, const float* __restrict__ aw,
    const float* __restrict__ vw, float* __restrict__ hpart)
{
    __shared__ unsigned short h1s[64 * 512];   // 64 KiB, swizzled [row][k]
    __shared__ unsigned short h0s[64 * 64];    // 8 KiB,  swizzled [row][k]

    const int tid  = threadIdx.x;
    const int wid  = tid >> 6;     // 0..7: col-block of 64
    const int lane = tid & 63;
    const int lr = lane & 15;
    const int kg = lane >> 4;
    const int b0 = blockIdx.x * 64;

    // ---- stage h0 tile: 8 KB, inverse-swizzled source, linear LDS dest ----
    {
        int offb  = tid << 4;
        int loffb = offb ^ (((offb >> 7) & 7) << 4);
        int row = loffb >> 7;            // 0..63
        int kel = (loffb & 127) >> 1;    // element offset, multiple of 8
        int ldsbyte = (wid * 64) << 4;   // wave-uniform base
        gload_lds16(h0b + (size_t)(b0 + row) * 64 + kel, (char*)h0s + ldsbyte);
    }
    __syncthreads();

    f32x4 acc[4][4];
#pragma unroll
    for (int m = 0; m < 4; ++m)
#pragma unroll
        for (int n = 0; n < 4; ++n) acc[m][n] = (f32x4){0.f, 0.f, 0.f, 0.f};

    // ---- phase 1: h1 = relu(h0 @ w1^T + b1), K=64 ----
#pragma unroll
    for (int ks = 0; ks < 2; ++ks) {
        int kbyte = ks * 64 + kg * 16;
        short8 af[4];
#pragma unroll
        for (int m = 0; m < 4; ++m) {
            int row = m * 16 + lr;
            int a = ((row << 7) + kbyte) ^ ((row & 7) << 4);
            af[m] = *(const short8*)((const char*)h0s + a);
        }
        short8 bfr[4];
#pragma unroll
        for (int n = 0; n < 4; ++n) {
            int col = wid * 64 + n * 16 + lr;
            bfr[n] = *(const short8*)(w1b + (size_t)col * 64 + ks * 32 + kg * 8);
        }
#pragma unroll
        for (int m = 0; m < 4; ++m)
#pragma unroll
            for (int n = 0; n < 4; ++n)
                acc[m][n] = __builtin_amdgcn_mfma_f32_16x16x32_bf16(
                    af[m], bfr[n], acc[m][n], 0, 0, 0);
    }

    // bias + relu -> bf16 -> swizzled LDS h1 tile (row stride 1024 B)
#pragma unroll
    for (int n = 0; n < 4; ++n) {
        int col = wid * 64 + n * 16 + lr;
        float b1v = b1[col];
#pragma unroll
        for (int m = 0; m < 4; ++m) {
#pragma unroll
            for (int r = 0; r < 4; ++r) {
                int row = m * 16 + kg * 4 + r;
                int byte = ((row << 10) + col * 2) ^ ((row & 7) << 4);
                *(unsigned short*)((char*)h1s + byte) =
                    f2bf(fmaxf(acc[m][n][r] + b1v, 0.f));
            }
        }
    }
    __syncthreads();    // h1 tile complete

    // ---- phase 2: K=512, A from LDS, B from L1/L2, 1-deep register prefetch ----
#pragma unroll
    for (int m = 0; m < 4; ++m)
#pragma unroll
        for (int n = 0; n < 4; ++n) acc[m][n] = (f32x4){0.f, 0.f, 0.f, 0.f};

    short8 aA[4], bA[4];
#pragma unroll
    for (int m = 0; m < 4; ++m) {
        int row = m * 16 + lr;
        int a = ((row << 10) + kg * 16) ^ ((row & 7) << 4);
        aA[m] = *(const short8*)((const char*)h1s + a);
    }
#pragma unroll
    for (int n = 0; n < 4; ++n) {
        int col = wid * 64 + n * 16 + lr;
        bA[n] = *(const short8*)(w2b + (size_t)col * 512 + kg * 8);
    }

#pragma unroll
    for (int kc = 0; kc < 16; ++kc) {
        short8 aB[4], bB[4];
        if (kc < 15) {
            int kb2 = (kc + 1) * 64 + kg * 16;
#pragma unroll
            for (int m = 0; m < 4; ++m) {
                int row = m * 16 + lr;
                int a = ((row << 10) + kb2) ^ ((row & 7) << 4);
                aB[m] = *(const short8*)((const char*)h1s + a);
            }
#pragma unroll
            for (int n = 0; n < 4; ++n) {
                int col = wid * 64 + n * 16 + lr;
                bB[n] = *(const short8*)(w2b + (size_t)col * 512 + (kc + 1) * 32 + kg * 8);
            }
        }
        __builtin_amdgcn_s_setprio(1);
#pragma unroll
        for (int m = 0; m < 4; ++m)
#pragma unroll
            for (int n = 0; n < 4; ++n)
                acc[m][n] = __builtin_amdgcn_mfma_f32_16x16x32_bf16(
                    aA[m], bA[n], acc[m][n], 0, 0, 0);
        __builtin_amdgcn_s_setprio(0);
        if (kc < 15) {
#pragma unroll
            for (int m = 0; m < 4; ++m) aA[m] = aB[m];
#pragma unroll
            for (int n = 0; n < 4; ++n) bA[n] = bB[n];
        }
    }

    // ---- fused heads epilogue: bias+relu (fp32), dot with head weights ----
#pragma unroll
    for (int n = 0; n < 4; ++n) {
        int col = wid * 64 + n * 16 + lr;
        float b2v = b2[col];
#pragma unroll
        for (int m = 0; m < 4; ++m)
#pragma unroll
            for (int r = 0; r < 4; ++r)
                acc[m][n][r] = fmaxf(acc[m][n][r] + b2v, 0.f);
    }

    float hwv[5][4];
#pragma unroll
    for (int n = 0; n < 4; ++n) {
        int col = wid * 64 + n * 16 + lr;
        hwv[0][n] = aw[col];
        hwv[1][n] = aw[512 + col];
        hwv[2][n] = aw[1024 + col];
        hwv[3][n] = aw[1536 + col];
        hwv[4][n] = vw[col];
    }
    float* hp = hpart + (size_t)wid * (BB * 5);
#pragma unroll
    for (int hm = 0; hm < 5; ++hm) {
        f32x4 p[4];
#pragma unroll
        for (int m = 0; m < 4; ++m) {
            p[m] = acc[m][0] * hwv[hm][0];
            p[m] += acc[m][1] * hwv[hm][1];
            p[m] += acc[m][2] * hwv[hm][2];
            p[m] += acc[m][3] * hwv[hm][3];
        }
#pragma unroll
        for (int d = 1; d < 16; d <<= 1)
#pragma unroll
            for (int m = 0; m < 4; ++m)
#pragma unroll
                for (int r = 0; r < 4; ++r)
                    p[m][r] += __shfl_xor(p[m][r], d);
        if (lr == 0) {
#pragma unroll
            for (int m = 0; m < 4; ++m)
#pragma unroll
                for (int r = 0; r < 4; ++r)
                    hp[(size_t)(b0 + m * 16 + kg * 4 + r) * 5 + hm] = p[m][r];
        }
    }
}

// ---------------- reduce 8 head-partial slots + bias -> out ----------------
__global__ __launch_bounds__(256) void k_hreduce(
    const float* __restrict__ hpart, const float* __restrict__ ab,
    const float* __restrict__ vb, float* __restrict__ out)
{
    int i = blockIdx.x * 256 + threadIdx.x;    // 0 .. BB*5-1, = b*5+hm
    int b = i / 5;
    int hm = i - b * 5;
    float s = 0.f;
#pragma unroll
    for (int g = 0; g < 8; ++g) s += hpart[(size_t)g * (BB * 5) + i];
    s += (hm < 4) ? ab[hm] : vb[0];
    if (hm < 4) out[(size_t)b * 4 + hm] = s;
    else        out[(size_t)BB * 4 + b] = s;
}

extern "C" void kernel_launch(void* const* d_in, const int* in_sizes, int n_in,
                              void* d_out, int out_size, void* d_ws, size_t ws_size,
                              hipStream_t stream)
{
    const float* x    = (const float*)d_in[0];
    const float* T    = (const float*)d_in[1];
    const float* K    = (const float*)d_in[2];
    const float* l1w  = (const float*)d_in[3];
    const float* l1b  = (const float*)d_in[4];
    const float* l2w  = (const float*)d_in[5];
    const float* l2b  = (const float*)d_in[6];
    const float* actw = (const float*)d_in[7];
    const float* actb = (const float*)d_in[8];
    const float* valw = (const float*)d_in[9];
    const float* valb = (const float*)d_in[10];
    float* out = (float*)d_out;

    char* ws = (char*)d_ws;
    unsigned short* h0b   = (unsigned short*)ws;                  // B*64 bf16   = 4,194,304 B
    unsigned short* h0T   = (unsigned short*)(ws + 4194304);      // 32*B bf16   = 2,097,152 B
    unsigned short* w2b   = (unsigned short*)(ws + 6291456);      // 512*512 bf16= 524,288 B
    unsigned short* w1b   = (unsigned short*)(ws + 6815744);      // 512*64 bf16 = 65,536 B
    float*          hpart = (float*)(ws + 6881280);               // 8*B*5 f32   = 5,242,880 B

    k_encode  <<<2048, 256, 0, stream>>>(x, T, K, h0T);
    k_cvtw    <<<288, 256, 0, stream>>>(l2w, w2b, l1w, w1b);
    k_pack    <<<BB / 256, 256, 0, stream>>>(h0T, x, h0b);
    k_fused   <<<512, 512, 0, stream>>>(h0b, w1b, w2b, l1b, l2b, actw, valw, hpart);
    k_hreduce <<<BB * 5 / 256, 256, 0, stream>>>(hpart, actb, valb, out);
}

// Round 11
// 68.427 us; speedup vs baseline: 1.3217x; 1.3217x over previous
//
#include <hip/hip_runtime.h>
#include <cstdint>
#include <cstddef>

#define BB   32768
#define DD   8
#define LLV  16
#define TBL  524288
#define HID  512

typedef __attribute__((ext_vector_type(8))) short short8;
typedef __attribute__((ext_vector_type(8))) unsigned short u16x8;
typedef __attribute__((ext_vector_type(4))) float f32x4;
typedef __attribute__((ext_vector_type(2))) float f32x2;

// primes mod 2^32
__device__ __constant__ uint32_t PR[8] = {
    2654436881u, 1620619981u, 1500450271u, 3267000013u,
    1459886047u, 4093082899u,  986956175u, 3628273133u
};

__device__ __forceinline__ unsigned short f2bf(float f) {
    uint32_t u = __float_as_uint(f);
    uint32_t r = (u + 0x7fffu + ((u >> 16) & 1u)) >> 16;   // RNE
    return (unsigned short)r;
}

__device__ __forceinline__ void gload_lds16(const void* gsrc, void* ldst) {
    __builtin_amdgcn_global_load_lds(
        (const __attribute__((address_space(1))) unsigned int*)gsrc,
        (__attribute__((address_space(3))) unsigned int*)ldst,
        16, 0, 0);
}

// per-sample: cumsum -> sort -> 9 vertex hashes + weights
__device__ __forceinline__ void enc_idx(const float xs[8], float Kl,
                                        uint32_t idx9[9], float w9[9])
{
    float fr[8];
    int   base[8];
    float cs = 0.f;
#pragma unroll
    for (int i2 = 0; i2 < 8; i2++) {
        cs += xs[i2];                 // sequential fp32 cumsum (matches np)
        float p = cs * Kl;
        fr[i2]   = p - truncf(p);
        base[i2] = (int)floorf(p);
    }

    float c[8];
#pragma unroll
    for (int i2 = 0; i2 < 8; i2++) c[i2] = fr[i2];
#define CE(a_, b_) { float lo_ = fminf(c[a_], c[b_]); float hi_ = fmaxf(c[a_], c[b_]); c[a_] = lo_; c[b_] = hi_; }
    CE(0,1) CE(2,3) CE(4,5) CE(6,7)
    CE(0,2) CE(1,3) CE(4,6) CE(5,7)
    CE(1,2) CE(5,6) CE(0,4) CE(3,7)
    CE(1,5) CE(2,6)
    CE(1,4) CE(3,6)
    CE(2,4) CE(3,5)
    CE(3,4)
#undef CE

    float prevc = 0.f;
#pragma unroll
    for (int j = 0; j < 9; j++) {
        float cj = (j < 8) ? c[j] : 1.0f;
        uint32_t h = 0;
        int prev = 0;
#pragma unroll
        for (int i2 = 0; i2 < 8; i2++) {
            int ai = base[i2] + (fr[i2] >= cj ? 1 : 0);
            h ^= (uint32_t)(ai - prev) * PR[i2];
            prev = ai;
        }
        idx9[j] = h & (TBL - 1);
        w9[j]   = cj - prevc;
        prevc   = cj;
    }
}

// ---------------- encoding: level-major, asm-batched gathers ----------------
__global__ __launch_bounds__(256) void k_encode(
    const float* __restrict__ x, const float* __restrict__ T,
    const float* __restrict__ Karr, unsigned short* __restrict__ h0T)
{
    int i = blockIdx.x;
    int l = (i & 7) + ((i >> 10) << 3);
    int b = ((i & 1023) >> 3) * 256 + threadIdx.x;

    const float4 x0 = *(const float4*)(x + (size_t)b * DD);
    const float4 x1 = *(const float4*)(x + (size_t)b * DD + 4);
    float xs[8] = {x0.x, x0.y, x0.z, x0.w, x1.x, x1.y, x1.z, x1.w};

    float Kl = Karr[l];
    const f32x2* Tl = (const f32x2*)(T + ((size_t)l * TBL) * 2);

    uint32_t idx9[9];
    float    w9[9];
    enc_idx(xs, Kl, idx9, w9);

    f32x2 t0, t1, t2, t3, t4, t5, t6, t7, t8;
#define GL(n) asm volatile("global_load_dwordx2 %0, %1, off" \
                           : "=v"(t##n) : "v"(Tl + idx9[n]));
    GL(0) GL(1) GL(2) GL(3) GL(4) GL(5) GL(6) GL(7) GL(8)
#undef GL
    asm volatile("s_waitcnt vmcnt(0)"
        : "+v"(t0), "+v"(t1), "+v"(t2), "+v"(t3), "+v"(t4),
          "+v"(t5), "+v"(t6), "+v"(t7), "+v"(t8));
    __builtin_amdgcn_sched_barrier(0);

    float f0, f1;
    f0 = t0[0] * w9[0];  f1 = t0[1] * w9[0];
    f0 = fmaf(t1[0], w9[1], f0); f1 = fmaf(t1[1], w9[1], f1);
    f0 = fmaf(t2[0], w9[2], f0); f1 = fmaf(t2[1], w9[2], f1);
    f0 = fmaf(t3[0], w9[3], f0); f1 = fmaf(t3[1], w9[3], f1);
    f0 = fmaf(t4[0], w9[4], f0); f1 = fmaf(t4[1], w9[4], f1);
    f0 = fmaf(t5[0], w9[5], f0); f1 = fmaf(t5[1], w9[5], f1);
    f0 = fmaf(t6[0], w9[6], f0); f1 = fmaf(t6[1], w9[6], f1);
    f0 = fmaf(t7[0], w9[7], f0); f1 = fmaf(t7[1], w9[7], f1);
    f0 = fmaf(t8[0], w9[8], f0); f1 = fmaf(t8[1], w9[8], f1);
    f0 /= Kl;
    f1 /= Kl;

    h0T[(size_t)(l * 2 + 0) * BB + b] = f2bf(f0);
    h0T[(size_t)(l * 2 + 1) * BB + b] = f2bf(f1);
}

// ---------------- pack: planes + x -> row-major bf16 [B][64] (zero-padded K) ----
__global__ __launch_bounds__(256) void k_pack(
    const unsigned short* __restrict__ h0T, const float* __restrict__ x,
    unsigned short* __restrict__ h0b)
{
    int b = blockIdx.x * 256 + threadIdx.x;
    unsigned short row[64];
    const float4 x0 = *(const float4*)(x + (size_t)b * 8);
    const float4 x1 = *(const float4*)(x + (size_t)b * 8 + 4);
    row[0] = f2bf(x0.x); row[1] = f2bf(x0.y); row[2] = f2bf(x0.z); row[3] = f2bf(x0.w);
    row[4] = f2bf(x1.x); row[5] = f2bf(x1.y); row[6] = f2bf(x1.z); row[7] = f2bf(x1.w);
#pragma unroll
    for (int p = 0; p < 32; p++) row[8 + p] = h0T[(size_t)p * BB + b];
#pragma unroll
    for (int c = 40; c < 64; c++) row[c] = 0;
#pragma unroll
    for (int i = 0; i < 8; i++)
        *(u16x8*)(h0b + (size_t)b * 64 + i * 8) = *(u16x8*)(row + i * 8);
}

// ---- weight converts into MFMA-fragment order: frag(col,kc,kg) @ ((kc*512+col)*4+kg)*8 elems ----
__global__ __launch_bounds__(256) void k_cvtw(
    const float* __restrict__ w2, unsigned short* __restrict__ w2p,
    const float* __restrict__ w1, unsigned short* __restrict__ w1p)
{
    int bid = blockIdx.x;
    if (bid < 128) {
        // w2: 512 cols x 16 kc x 4 kg fragments
        int u  = bid * 256 + threadIdx.x;     // kg fastest, then kc, then col
        int kg = u & 3, kc = (u >> 2) & 15, c = u >> 6;
        const float* src = w2 + (size_t)c * 512 + kc * 32 + kg * 8;
        unsigned short fr[8];
#pragma unroll
        for (int e = 0; e < 8; ++e) fr[e] = f2bf(src[e]);
        *(u16x8*)(w2p + ((((size_t)kc * 512 + c) * 4 + kg) << 3)) = *(u16x8*)fr;
    } else {
        // w1: 512 cols x 2 ks x 4 kg fragments, K padded 40->64 with zeros
        int u  = (bid - 128) * 256 + threadIdx.x;   // 4096 total
        int kg = u & 3, ks = (u >> 2) & 1, c = u >> 3;
        int kbase = ks * 32 + kg * 8;
        unsigned short fr[8];
#pragma unroll
        for (int e = 0; e < 8; ++e) {
            int k = kbase + e;
            fr[e] = (k < 40) ? f2bf(w1[(size_t)c * 40 + k]) : (unsigned short)0;
        }
        *(u16x8*)(w1p + ((((size_t)ks * 512 + c) * 4 + kg) << 3)) = *(u16x8*)fr;
    }
}

// ---------------- fused MLP: 128 samples/block, 8 waves (2x4), h1 in 128KB LDS ----------------
// B-operands come from fragment-packed w1p/w2p: each wave's load = contiguous 1KB.
// Phase-2: 16 fully-unrolled steps, two named register sets (dbuf), loads(k+1)
// pinned before MFMAs(k) with sched_barrier.
__global__ __launch_bounds__(512, 2) void k_fused(
    const unsigned short* __restrict__ h0b, const unsigned short* __restrict__ w1p,
    const unsigned short* __restrict__ w2p, const float* __restrict__ b1,
    const float* __restrict__ b2, const float* __restrict__ aw,
    const float* __restrict__ vw, float* __restrict__ hpart)
{
    __shared__ unsigned short h1s[128 * 512];   // 128 KiB, swizzled [row][k]
    __shared__ unsigned short h0s[128 * 64];    // 16 KiB,  swizzled [row][k]

    const int tid  = threadIdx.x;
    const int wid  = tid >> 6;
    const int lane = tid & 63;
    const int wm = wid >> 2, wn = wid & 3;
    const int lr = lane & 15;
    const int kg = lane >> 4;
    const int b0 = blockIdx.x * 128;

    // ---- stage h0 tile: 16 KB, inverse-swizzled source, linear LDS dest ----
#pragma unroll
    for (int it = 0; it < 2; ++it) {
        int offb  = (it * 512 + tid) << 4;
        int loffb = offb ^ (((offb >> 7) & 7) << 4);
        int row = loffb >> 7;            // 0..127
        int kel = (loffb & 127) >> 1;    // element offset, multiple of 8
        int ldsbyte = ((it * 512) + (wid * 64)) << 4;
        gload_lds16(h0b + (size_t)(b0 + row) * 64 + kel, (char*)h0s + ldsbyte);
    }
    __syncthreads();

    f32x4 acc[4][8];
#pragma unroll
    for (int m = 0; m < 4; ++m)
#pragma unroll
        for (int n = 0; n < 8; ++n) acc[m][n] = (f32x4){0.f, 0.f, 0.f, 0.f};

    // ---- phase 1: h1 = relu(h0 @ w1^T + b1), K=64 ----
#pragma unroll
    for (int ks = 0; ks < 2; ++ks) {
        int kbyte = ks * 64 + kg * 16;
        short8 af[4];
#pragma unroll
        for (int m = 0; m < 4; ++m) {
            int row = wm * 64 + m * 16 + lr;
            int a = ((row << 7) + kbyte) ^ ((row & 7) << 4);
            af[m] = *(const short8*)((const char*)h0s + a);
        }
        short8 bfr[8];
#pragma unroll
        for (int n = 0; n < 8; ++n) {
            int col = wn * 128 + n * 16 + lr;
            bfr[n] = *(const short8*)(w1p + ((((size_t)ks * 512 + col) * 4 + kg) << 3));
        }
#pragma unroll
        for (int m = 0; m < 4; ++m)
#pragma unroll
            for (int n = 0; n < 8; ++n)
                acc[m][n] = __builtin_amdgcn_mfma_f32_16x16x32_bf16(
                    af[m], bfr[n], acc[m][n], 0, 0, 0);
    }

    // bias + relu -> bf16 -> swizzled LDS h1 tile (row stride 1024 B)
#pragma unroll
    for (int n = 0; n < 8; ++n) {
        int col = wn * 128 + n * 16 + lr;
        float b1v = b1[col];
#pragma unroll
        for (int m = 0; m < 4; ++m) {
#pragma unroll
            for (int r = 0; r < 4; ++r) {
                int row = wm * 64 + m * 16 + kg * 4 + r;
                int byte = ((row << 10) + col * 2) ^ ((row & 7) << 4);
                *(unsigned short*)((char*)h1s + byte) =
                    f2bf(fmaxf(acc[m][n][r] + b1v, 0.f));
            }
        }
    }
    __syncthreads();    // h1 tile complete

    // ---- phase 2: K=512, A from LDS, B from packed w2p, 1-deep named dbuf ----
#pragma unroll
    for (int m = 0; m < 4; ++m)
#pragma unroll
        for (int n = 0; n < 8; ++n) acc[m][n] = (f32x4){0.f, 0.f, 0.f, 0.f};

    short8 aX[4], bX[8], aY[4], bY[8];

#define LDA(dst, kc)                                                            \
    _Pragma("unroll")                                                           \
    for (int m = 0; m < 4; ++m) {                                               \
        int row = wm * 64 + m * 16 + lr;                                        \
        int a = (((row << 10) + (kc) * 64 + kg * 16)) ^ ((row & 7) << 4);       \
        dst[m] = *(const short8*)((const char*)h1s + a);                        \
    }
#define LDB(dst, kc)                                                            \
    _Pragma("unroll")                                                           \
    for (int n = 0; n < 8; ++n) {                                               \
        int col = wn * 128 + n * 16 + lr;                                       \
        dst[n] = *(const short8*)(w2p + ((((size_t)(kc) * 512 + col) * 4 + kg) << 3)); \
    }
#define MM(aa, bb)                                                              \
    __builtin_amdgcn_sched_barrier(0);                                          \
    __builtin_amdgcn_s_setprio(1);                                              \
    _Pragma("unroll")                                                           \
    for (int m = 0; m < 4; ++m)                                                 \
        _Pragma("unroll")                                                       \
        for (int n = 0; n < 8; ++n)                                             \
            acc[m][n] = __builtin_amdgcn_mfma_f32_16x16x32_bf16(                \
                aa[m], bb[n], acc[m][n], 0, 0, 0);                              \
    __builtin_amdgcn_s_setprio(0);

    LDA(aX, 0)  LDB(bX, 0)
    LDA(aY, 1)  LDB(bY, 1)  MM(aX, bX)
    LDA(aX, 2)  LDB(bX, 2)  MM(aY, bY)
    LDA(aY, 3)  LDB(bY, 3)  MM(aX, bX)
    LDA(aX, 4)  LDB(bX, 4)  MM(aY, bY)
    LDA(aY, 5)  LDB(bY, 5)  MM(aX, bX)
    LDA(aX, 6)  LDB(bX, 6)  MM(aY, bY)
    LDA(aY, 7)  LDB(bY, 7)  MM(aX, bX)
    LDA(aX, 8)  LDB(bX, 8)  MM(aY, bY)
    LDA(aY, 9)  LDB(bY, 9)  MM(aX, bX)
    LDA(aX, 10) LDB(bX, 10) MM(aY, bY)
    LDA(aY, 11) LDB(bY, 11) MM(aX, bX)
    LDA(aX, 12) LDB(bX, 12) MM(aY, bY)
    LDA(aY, 13) LDB(bY, 13) MM(aX, bX)
    LDA(aX, 14) LDB(bX, 14) MM(aY, bY)
    LDA(aY, 15) LDB(bY, 15) MM(aX, bX)
    MM(aY, bY)
#undef LDA
#undef LDB
#undef MM

    // ---- fused heads epilogue: bias+relu (fp32), dot with head weights ----
#pragma unroll
    for (int n = 0; n < 8; ++n) {
        int col = wn * 128 + n * 16 + lr;
        float b2v = b2[col];
#pragma unroll
        for (int m = 0; m < 4; ++m)
#pragma unroll
            for (int r = 0; r < 4; ++r)
                acc[m][n][r] = fmaxf(acc[m][n][r] + b2v, 0.f);
    }

    float hwv[5][8];
#pragma unroll
    for (int n = 0; n < 8; ++n) {
        int col = wn * 128 + n * 16 + lr;
        hwv[0][n] = aw[col];
        hwv[1][n] = aw[512 + col];
        hwv[2][n] = aw[1024 + col];
        hwv[3][n] = aw[1536 + col];
        hwv[4][n] = vw[col];
    }
    float* hp = hpart + (size_t)wn * (BB * 5);
#pragma unroll
    for (int hm = 0; hm < 5; ++hm) {
        f32x4 p[4];
#pragma unroll
        for (int m = 0; m < 4; ++m) {
            p[m] = acc[m][0] * hwv[hm][0];
#pragma unroll
            for (int n = 1; n < 8; ++n) p[m] += acc[m][n] * hwv[hm][n];
        }
#pragma unroll
        for (int d = 1; d < 16; d <<= 1)
#pragma unroll
            for (int m = 0; m < 4; ++m)
#pragma unroll
                for (int r = 0; r < 4; ++r)
                    p[m][r] += __shfl_xor(p[m][r], d);
        if (lr == 0) {
#pragma unroll
            for (int m = 0; m < 4; ++m)
#pragma unroll
                for (int r = 0; r < 4; ++r)
                    hp[(size_t)(b0 + wm * 64 + m * 16 + kg * 4 + r) * 5 + hm] = p[m][r];
        }
    }
}

// ---------------- reduce 4 head-partial slots + bias -> out ----------------
__global__ __launch_bounds__(256) void k_hreduce(
    const float* __restrict__ hpart, const float* __restrict__ ab,
    const float* __restrict__ vb, float* __restrict__ out)
{
    int i = blockIdx.x * 256 + threadIdx.x;    // 0 .. BB*5-1, = b*5+hm
    int b = i / 5;
    int hm = i - b * 5;
    float s = 0.f;
#pragma unroll
    for (int g = 0; g < 4; ++g) s += hpart[(size_t)g * (BB * 5) + i];
    s += (hm < 4) ? ab[hm] : vb[0];
    if (hm < 4) out[(size_t)b * 4 + hm] = s;
    else        out[(size_t)BB * 4 + b] = s;
}

extern "C" void kernel_launch(void* const* d_in, const int* in_sizes, int n_in,
                              void* d_out, int out_size, void* d_ws, size_t ws_size,
                              hipStream_t stream)
{
    const float* x    = (const float*)d_in[0];
    const float* T    = (const float*)d_in[1];
    const float* K    = (const float*)d_in[2];
    const float* l1w  = (const float*)d_in[3];
    const float* l1b  = (const float*)d_in[4];
    const float* l2w  = (const float*)d_in[5];
    const float* l2b  = (const float*)d_in[6];
    const float* actw = (const float*)d_in[7];
    const float* actb = (const float*)d_in[8];
    const float* valw = (const float*)d_in[9];
    const float* valb = (const float*)d_in[10];
    float* out = (float*)d_out;

    char* ws = (char*)d_ws;
    unsigned short* h0b   = (unsigned short*)ws;                  // B*64 bf16   = 4,194,304 B
    unsigned short* h0T   = (unsigned short*)(ws + 4194304);      // 32*B bf16   = 2,097,152 B
    unsigned short* w2p   = (unsigned short*)(ws + 6291456);      // 512*512 bf16= 524,288 B
    unsigned short* w1p   = (unsigned short*)(ws + 6815744);      // 512*64 bf16 = 65,536 B
    float*          hpart = (float*)(ws + 6881280);               // 4*B*5 f32   = 2,621,440 B

    k_encode  <<<2048, 256, 0, stream>>>(x, T, K, h0T);
    k_cvtw    <<<144, 256, 0, stream>>>(l2w, w2p, l1w, w1p);
    k_pack    <<<BB / 256, 256, 0, stream>>>(h0T, x, h0b);
    k_fused   <<<256, 512, 0, stream>>>(h0b, w1p, w2p, l1b, l2b, actw, valw, hpart);
    k_hreduce <<<BB * 5 / 256, 256, 0, stream>>>(hpart, actb, valb, out);
}

// Round 12
// 61.896 us; speedup vs baseline: 1.4611x; 1.1055x over previous
//
#include <hip/hip_runtime.h>
#include <cstdint>
#include <cstddef>

#define BB   32768
#define DD   8
#define LLV  16
#define TBL  524288
#define HID  512

typedef __attribute__((ext_vector_type(8))) short short8;
typedef __attribute__((ext_vector_type(8))) unsigned short u16x8;
typedef __attribute__((ext_vector_type(4))) float f32x4;
typedef __attribute__((ext_vector_type(2))) float f32x2;

// primes mod 2^32
__device__ __constant__ uint32_t PR[8] = {
    2654436881u, 1620619981u, 1500450271u, 3267000013u,
    1459886047u, 4093082899u,  986956175u, 3628273133u
};

__device__ __forceinline__ unsigned short f2bf(float f) {
    uint32_t u = __float_as_uint(f);
    uint32_t r = (u + 0x7fffu + ((u >> 16) & 1u)) >> 16;   // RNE
    return (unsigned short)r;
}

// per-sample: cumsum -> sort -> 9 vertex hashes + weights
__device__ __forceinline__ void enc_idx(const float xs[8], float Kl,
                                        uint32_t idx9[9], float w9[9])
{
    float fr[8];
    int   base[8];
    float cs = 0.f;
#pragma unroll
    for (int i2 = 0; i2 < 8; i2++) {
        cs += xs[i2];                 // sequential fp32 cumsum (matches np)
        float p = cs * Kl;
        fr[i2]   = p - truncf(p);
        base[i2] = (int)floorf(p);
    }

    float c[8];
#pragma unroll
    for (int i2 = 0; i2 < 8; i2++) c[i2] = fr[i2];
#define CE(a_, b_) { float lo_ = fminf(c[a_], c[b_]); float hi_ = fmaxf(c[a_], c[b_]); c[a_] = lo_; c[b_] = hi_; }
    CE(0,1) CE(2,3) CE(4,5) CE(6,7)
    CE(0,2) CE(1,3) CE(4,6) CE(5,7)
    CE(1,2) CE(5,6) CE(0,4) CE(3,7)
    CE(1,5) CE(2,6)
    CE(1,4) CE(3,6)
    CE(2,4) CE(3,5)
    CE(3,4)
#undef CE

    float prevc = 0.f;
#pragma unroll
    for (int j = 0; j < 9; j++) {
        float cj = (j < 8) ? c[j] : 1.0f;
        uint32_t h = 0;
        int prev = 0;
#pragma unroll
        for (int i2 = 0; i2 < 8; i2++) {
            int ai = base[i2] + (fr[i2] >= cj ? 1 : 0);
            h ^= (uint32_t)(ai - prev) * PR[i2];
            prev = ai;
        }
        idx9[j] = h & (TBL - 1);
        w9[j]   = cj - prevc;
        prevc   = cj;
    }
}

// ---------------- encoding: level-major, asm-batched gathers ----------------
__global__ __launch_bounds__(256) void k_encode(
    const float* __restrict__ x, const float* __restrict__ T,
    const float* __restrict__ Karr, unsigned short* __restrict__ h0T)
{
    int i = blockIdx.x;
    int l = (i & 7) + ((i >> 10) << 3);
    int b = ((i & 1023) >> 3) * 256 + threadIdx.x;

    const float4 x0 = *(const float4*)(x + (size_t)b * DD);
    const float4 x1 = *(const float4*)(x + (size_t)b * DD + 4);
    float xs[8] = {x0.x, x0.y, x0.z, x0.w, x1.x, x1.y, x1.z, x1.w};

    float Kl = Karr[l];
    const f32x2* Tl = (const f32x2*)(T + ((size_t)l * TBL) * 2);

    uint32_t idx9[9];
    float    w9[9];
    enc_idx(xs, Kl, idx9, w9);

    f32x2 t0, t1, t2, t3, t4, t5, t6, t7, t8;
#define GL(n) asm volatile("global_load_dwordx2 %0, %1, off" \
                           : "=v"(t##n) : "v"(Tl + idx9[n]));
    GL(0) GL(1) GL(2) GL(3) GL(4) GL(5) GL(6) GL(7) GL(8)
#undef GL
    asm volatile("s_waitcnt vmcnt(0)"
        : "+v"(t0), "+v"(t1), "+v"(t2), "+v"(t3), "+v"(t4),
          "+v"(t5), "+v"(t6), "+v"(t7), "+v"(t8));
    __builtin_amdgcn_sched_barrier(0);

    float f0, f1;
    f0 = t0[0] * w9[0];  f1 = t0[1] * w9[0];
    f0 = fmaf(t1[0], w9[1], f0); f1 = fmaf(t1[1], w9[1], f1);
    f0 = fmaf(t2[0], w9[2], f0); f1 = fmaf(t2[1], w9[2], f1);
    f0 = fmaf(t3[0], w9[3], f0); f1 = fmaf(t3[1], w9[3], f1);
    f0 = fmaf(t4[0], w9[4], f0); f1 = fmaf(t4[1], w9[4], f1);
    f0 = fmaf(t5[0], w9[5], f0); f1 = fmaf(t5[1], w9[5], f1);
    f0 = fmaf(t6[0], w9[6], f0); f1 = fmaf(t6[1], w9[6], f1);
    f0 = fmaf(t7[0], w9[7], f0); f1 = fmaf(t7[1], w9[7], f1);
    f0 = fmaf(t8[0], w9[8], f0); f1 = fmaf(t8[1], w9[8], f1);
    f0 /= Kl;
    f1 /= Kl;

    h0T[(size_t)(l * 2 + 0) * BB + b] = f2bf(f0);
    h0T[(size_t)(l * 2 + 1) * BB + b] = f2bf(f1);
}

// ---- weight converts into MFMA-fragment order: frag(col,kc,kg) @ ((kc*512+col)*4+kg)*8 elems ----
__global__ __launch_bounds__(256) void k_cvtw(
    const float* __restrict__ w2, unsigned short* __restrict__ w2p,
    const float* __restrict__ w1, unsigned short* __restrict__ w1p)
{
    int bid = blockIdx.x;
    if (bid < 128) {
        // w2: 512 cols x 16 kc x 4 kg fragments
        int u  = bid * 256 + threadIdx.x;     // kg fastest, then kc, then col
        int kg = u & 3, kc = (u >> 2) & 15, c = u >> 6;
        const float* src = w2 + (size_t)c * 512 + kc * 32 + kg * 8;
        unsigned short fr[8];
#pragma unroll
        for (int e = 0; e < 8; ++e) fr[e] = f2bf(src[e]);
        *(u16x8*)(w2p + ((((size_t)kc * 512 + c) * 4 + kg) << 3)) = *(u16x8*)fr;
    } else {
        // w1: 512 cols x 2 ks x 4 kg fragments, K padded 40->64 with zeros
        int u  = (bid - 128) * 256 + threadIdx.x;   // 4096 total
        int kg = u & 3, ks = (u >> 2) & 1, c = u >> 3;
        int kbase = ks * 32 + kg * 8;
        unsigned short fr[8];
#pragma unroll
        for (int e = 0; e < 8; ++e) {
            int k = kbase + e;
            fr[e] = (k < 40) ? f2bf(w1[(size_t)c * 40 + k]) : (unsigned short)0;
        }
        *(u16x8*)(w1p + ((((size_t)ks * 512 + c) * 4 + kg) << 3)) = *(u16x8*)fr;
    }
}

// ---------------- fused MLP: stages h0T+x itself, writes out directly ----------------
// 256 blocks x 512 threads (8 waves 2x4), h1 tile in 128 KB LDS (1 block/CU).
// B-operands from fragment-packed w1p/w2p (contiguous 1KB wave-loads, L2-hot).
// Phase-2: 16 unrolled steps, named dbuf regs, loads(k+1) before MFMAs(k).
// Epilogue: per-wn head partials -> LDS -> cross-wn sum -> out (no hreduce kernel).
__global__ __launch_bounds__(512, 2) void k_fused(
    const unsigned short* __restrict__ h0T, const float* __restrict__ x,
    const unsigned short* __restrict__ w1p, const unsigned short* __restrict__ w2p,
    const float* __restrict__ b1, const float* __restrict__ b2,
    const float* __restrict__ aw, const float* __restrict__ ab,
    const float* __restrict__ vw, const float* __restrict__ vb,
    float* __restrict__ out)
{
    __shared__ unsigned short h1s[128 * 512];   // 128 KiB, swizzled [row][k]
    __shared__ unsigned short h0s[128 * 64];    // 16 KiB,  swizzled [row][k]; reused as spart

    const int tid  = threadIdx.x;
    const int wid  = tid >> 6;
    const int lane = tid & 63;
    const int wm = wid >> 2, wn = wid & 3;
    const int lr = lane & 15;
    const int kg = lane >> 4;
    const int b0 = blockIdx.x * 128;

    // ---- stage h0 tile straight from h0T planes + x (transpose via ds_writes) ----
    {
        // 32 planes x 128 samples: thread t covers plane t>>4, samples (t&15)*8..+8
        int p = tid >> 4, c = tid & 15;
        u16x8 v = *(const u16x8*)(h0T + (size_t)p * BB + b0 + c * 8);
#pragma unroll
        for (int e = 0; e < 8; ++e) {
            int row = c * 8 + e;
            int byte = ((row << 7) + (8 + p) * 2) ^ ((row & 7) << 4);
            *(unsigned short*)((char*)h0s + byte) = v[e];
        }
        if (tid < 128) {            // x rows -> cols 0..7 (one b128 per row)
            int row = tid;
            const float4 x0 = *(const float4*)(x + (size_t)(b0 + row) * 8);
            const float4 x1 = *(const float4*)(x + (size_t)(b0 + row) * 8 + 4);
            unsigned short xv[8] = {
                f2bf(x0.x), f2bf(x0.y), f2bf(x0.z), f2bf(x0.w),
                f2bf(x1.x), f2bf(x1.y), f2bf(x1.z), f2bf(x1.w)};
            *(u16x8*)((char*)h0s + ((row << 7) ^ ((row & 7) << 4))) = *(u16x8*)xv;
        } else {                    // zero-pad cols 40..63 (3 x 16B per row)
            int t2 = tid - 128;     // 0..383
            int row = t2 / 3, seg = t2 - row * 3;
            int byte = ((row << 7) + 80 + seg * 16) ^ ((row & 7) << 4);
            u16x8 z = {0, 0, 0, 0, 0, 0, 0, 0};
            *(u16x8*)((char*)h0s + byte) = z;
        }
    }
    __syncthreads();

    f32x4 acc[4][8];
#pragma unroll
    for (int m = 0; m < 4; ++m)
#pragma unroll
        for (int n = 0; n < 8; ++n) acc[m][n] = (f32x4){0.f, 0.f, 0.f, 0.f};

    // ---- phase 1: h1 = relu(h0 @ w1^T + b1), K=64 ----
#pragma unroll
    for (int ks = 0; ks < 2; ++ks) {
        int kbyte = ks * 64 + kg * 16;
        short8 af[4];
#pragma unroll
        for (int m = 0; m < 4; ++m) {
            int row = wm * 64 + m * 16 + lr;
            int a = ((row << 7) + kbyte) ^ ((row & 7) << 4);
            af[m] = *(const short8*)((const char*)h0s + a);
        }
        short8 bfr[8];
#pragma unroll
        for (int n = 0; n < 8; ++n) {
            int col = wn * 128 + n * 16 + lr;
            bfr[n] = *(const short8*)(w1p + ((((size_t)ks * 512 + col) * 4 + kg) << 3));
        }
#pragma unroll
        for (int m = 0; m < 4; ++m)
#pragma unroll
            for (int n = 0; n < 8; ++n)
                acc[m][n] = __builtin_amdgcn_mfma_f32_16x16x32_bf16(
                    af[m], bfr[n], acc[m][n], 0, 0, 0);
    }

    // bias + relu -> bf16 -> swizzled LDS h1 tile (row stride 1024 B)
#pragma unroll
    for (int n = 0; n < 8; ++n) {
        int col = wn * 128 + n * 16 + lr;
        float b1v = b1[col];
#pragma unroll
        for (int m = 0; m < 4; ++m) {
#pragma unroll
            for (int r = 0; r < 4; ++r) {
                int row = wm * 64 + m * 16 + kg * 4 + r;
                int byte = ((row << 10) + col * 2) ^ ((row & 7) << 4);
                *(unsigned short*)((char*)h1s + byte) =
                    f2bf(fmaxf(acc[m][n][r] + b1v, 0.f));
            }
        }
    }
    __syncthreads();    // h1 tile complete; h0s no longer read

    // ---- phase 2: K=512, A from LDS, B from packed w2p, 1-deep named dbuf ----
#pragma unroll
    for (int m = 0; m < 4; ++m)
#pragma unroll
        for (int n = 0; n < 8; ++n) acc[m][n] = (f32x4){0.f, 0.f, 0.f, 0.f};

    short8 aX[4], bX[8], aY[4], bY[8];

#define LDA(dst, kc)                                                            \
    _Pragma("unroll")                                                           \
    for (int m = 0; m < 4; ++m) {                                               \
        int row = wm * 64 + m * 16 + lr;                                        \
        int a = (((row << 10) + (kc) * 64 + kg * 16)) ^ ((row & 7) << 4);       \
        dst[m] = *(const short8*)((const char*)h1s + a);                        \
    }
#define LDB(dst, kc)                                                            \
    _Pragma("unroll")                                                           \
    for (int n = 0; n < 8; ++n) {                                               \
        int col = wn * 128 + n * 16 + lr;                                       \
        dst[n] = *(const short8*)(w2p + ((((size_t)(kc) * 512 + col) * 4 + kg) << 3)); \
    }
#define MM(aa, bb)                                                              \
    __builtin_amdgcn_sched_barrier(0);                                          \
    __builtin_amdgcn_s_setprio(1);                                              \
    _Pragma("unroll")                                                           \
    for (int m = 0; m < 4; ++m)                                                 \
        _Pragma("unroll")                                                       \
        for (int n = 0; n < 8; ++n)                                             \
            acc[m][n] = __builtin_amdgcn_mfma_f32_16x16x32_bf16(                \
                aa[m], bb[n], acc[m][n], 0, 0, 0);                              \
    __builtin_amdgcn_s_setprio(0);

    LDA(aX, 0)  LDB(bX, 0)
    LDA(aY, 1)  LDB(bY, 1)  MM(aX, bX)
    LDA(aX, 2)  LDB(bX, 2)  MM(aY, bY)
    LDA(aY, 3)  LDB(bY, 3)  MM(aX, bX)
    LDA(aX, 4)  LDB(bX, 4)  MM(aY, bY)
    LDA(aY, 5)  LDB(bY, 5)  MM(aX, bX)
    LDA(aX, 6)  LDB(bX, 6)  MM(aY, bY)
    LDA(aY, 7)  LDB(bY, 7)  MM(aX, bX)
    LDA(aX, 8)  LDB(bX, 8)  MM(aY, bY)
    LDA(aY, 9)  LDB(bY, 9)  MM(aX, bX)
    LDA(aX, 10) LDB(bX, 10) MM(aY, bY)
    LDA(aY, 11) LDB(bY, 11) MM(aX, bX)
    LDA(aX, 12) LDB(bX, 12) MM(aY, bY)
    LDA(aY, 13) LDB(bY, 13) MM(aX, bX)
    LDA(aX, 14) LDB(bX, 14) MM(aY, bY)
    LDA(aY, 15) LDB(bY, 15) MM(aX, bX)
    MM(aY, bY)
#undef LDA
#undef LDB
#undef MM

    // ---- epilogue: bias+relu (fp32), head dots, in-block cross-wn reduction ----
#pragma unroll
    for (int n = 0; n < 8; ++n) {
        int col = wn * 128 + n * 16 + lr;
        float b2v = b2[col];
#pragma unroll
        for (int m = 0; m < 4; ++m)
#pragma unroll
            for (int r = 0; r < 4; ++r)
                acc[m][n][r] = fmaxf(acc[m][n][r] + b2v, 0.f);
    }

    float hwv[5][8];
#pragma unroll
    for (int n = 0; n < 8; ++n) {
        int col = wn * 128 + n * 16 + lr;
        hwv[0][n] = aw[col];
        hwv[1][n] = aw[512 + col];
        hwv[2][n] = aw[1024 + col];
        hwv[3][n] = aw[1536 + col];
        hwv[4][n] = vw[col];
    }
    float* spart = (float*)h0s;               // [wn][hm][row] = 4*5*128 f32 = 10 KB
#pragma unroll
    for (int hm = 0; hm < 5; ++hm) {
        f32x4 p[4];
#pragma unroll
        for (int m = 0; m < 4; ++m) {
            p[m] = acc[m][0] * hwv[hm][0];
#pragma unroll
            for (int n = 1; n < 8; ++n) p[m] += acc[m][n] * hwv[hm][n];
        }
#pragma unroll
        for (int d = 1; d < 16; d <<= 1)
#pragma unroll
            for (int m = 0; m < 4; ++m)
#pragma unroll
                for (int r = 0; r < 4; ++r)
                    p[m][r] += __shfl_xor(p[m][r], d);
        if (lr == 0) {
#pragma unroll
            for (int m = 0; m < 4; ++m)
#pragma unroll
                for (int r = 0; r < 4; ++r)
                    spart[(wn * 5 + hm) * 128 + wm * 64 + m * 16 + kg * 4 + r] = p[m][r];
        }
    }
    __syncthreads();

    if (tid < 128) {
        int b = b0 + tid;
        float s[5];
#pragma unroll
        for (int hm = 0; hm < 5; ++hm) {
            float v = spart[(0 * 5 + hm) * 128 + tid] + spart[(1 * 5 + hm) * 128 + tid]
                    + spart[(2 * 5 + hm) * 128 + tid] + spart[(3 * 5 + hm) * 128 + tid];
            s[hm] = v;
        }
        float4 act = make_float4(s[0] + ab[0], s[1] + ab[1], s[2] + ab[2], s[3] + ab[3]);
        *(float4*)(out + (size_t)b * 4) = act;
        out[(size_t)BB * 4 + b] = s[4] + vb[0];
    }
}

extern "C" void kernel_launch(void* const* d_in, const int* in_sizes, int n_in,
                              void* d_out, int out_size, void* d_ws, size_t ws_size,
                              hipStream_t stream)
{
    const float* x    = (const float*)d_in[0];
    const float* T    = (const float*)d_in[1];
    const float* K    = (const float*)d_in[2];
    const float* l1w  = (const float*)d_in[3];
    const float* l1b  = (const float*)d_in[4];
    const float* l2w  = (const float*)d_in[5];
    const float* l2b  = (const float*)d_in[6];
    const float* actw = (const float*)d_in[7];
    const float* actb = (const float*)d_in[8];
    const float* valw = (const float*)d_in[9];
    const float* valb = (const float*)d_in[10];
    float* out = (float*)d_out;

    char* ws = (char*)d_ws;
    unsigned short* h0T = (unsigned short*)ws;                  // 32*B bf16   = 2,097,152 B
    unsigned short* w2p = (unsigned short*)(ws + 2097152);      // 512*512 bf16= 524,288 B
    unsigned short* w1p = (unsigned short*)(ws + 2621440);      // 512*64 bf16 = 65,536 B

    k_encode <<<2048, 256, 0, stream>>>(x, T, K, h0T);
    k_cvtw   <<<144, 256, 0, stream>>>(l2w, w2p, l1w, w1p);
    k_fused  <<<256, 512, 0, stream>>>(h0T, x, w1p, w2p, l1b, l2b,
                                       actw, actb, valw, valb, out);
}

// Round 13
// 60.900 us; speedup vs baseline: 1.4850x; 1.0164x over previous
//
#include <hip/hip_runtime.h>
#include <cstdint>
#include <cstddef>

#define BB   32768
#define DD   8
#define LLV  16
#define TBL  524288
#define HID  512

typedef __attribute__((ext_vector_type(8))) short short8;
typedef __attribute__((ext_vector_type(8))) unsigned short u16x8;
typedef __attribute__((ext_vector_type(4))) float f32x4;
typedef __attribute__((ext_vector_type(2))) float f32x2;

// primes mod 2^32
__device__ __constant__ uint32_t PR[8] = {
    2654436881u, 1620619981u, 1500450271u, 3267000013u,
    1459886047u, 4093082899u,  986956175u, 3628273133u
};

__device__ __forceinline__ unsigned short f2bf(float f) {
    uint32_t u = __float_as_uint(f);
    uint32_t r = (u + 0x7fffu + ((u >> 16) & 1u)) >> 16;   // RNE
    return (unsigned short)r;
}

// per-sample: cumsum -> sort -> 9 vertex hashes + weights
__device__ __forceinline__ void enc_idx(const float xs[8], float Kl,
                                        uint32_t idx9[9], float w9[9])
{
    float fr[8];
    int   base[8];
    float cs = 0.f;
#pragma unroll
    for (int i2 = 0; i2 < 8; i2++) {
        cs += xs[i2];                 // sequential fp32 cumsum (matches np)
        float p = cs * Kl;
        fr[i2]   = p - truncf(p);
        base[i2] = (int)floorf(p);
    }

    float c[8];
#pragma unroll
    for (int i2 = 0; i2 < 8; i2++) c[i2] = fr[i2];
#define CE(a_, b_) { float lo_ = fminf(c[a_], c[b_]); float hi_ = fmaxf(c[a_], c[b_]); c[a_] = lo_; c[b_] = hi_; }
    CE(0,1) CE(2,3) CE(4,5) CE(6,7)
    CE(0,2) CE(1,3) CE(4,6) CE(5,7)
    CE(1,2) CE(5,6) CE(0,4) CE(3,7)
    CE(1,5) CE(2,6)
    CE(1,4) CE(3,6)
    CE(2,4) CE(3,5)
    CE(3,4)
#undef CE

    float prevc = 0.f;
#pragma unroll
    for (int j = 0; j < 9; j++) {
        float cj = (j < 8) ? c[j] : 1.0f;
        uint32_t h = 0;
        int prev = 0;
#pragma unroll
        for (int i2 = 0; i2 < 8; i2++) {
            int ai = base[i2] + (fr[i2] >= cj ? 1 : 0);
            h ^= (uint32_t)(ai - prev) * PR[i2];
            prev = ai;
        }
        idx9[j] = h & (TBL - 1);
        w9[j]   = cj - prevc;
        prevc   = cj;
    }
}

// ---------------- encoding (blocks 0..2047) + weight converts (blocks 2048..2191) ----
// Encode: level-major, block i -> level (i&7)+8*(i>>10); xcd=i%8 keeps each
// XCD's L2 on ~1 level-table at a time. All 9 gathers forced in flight (asm).
// Convert blocks ride in encode's tail (latency-bound, idle issue slots).
__global__ __launch_bounds__(256) void k_encode(
    const float* __restrict__ x, const float* __restrict__ T,
    const float* __restrict__ Karr, unsigned short* __restrict__ h0T,
    const float* __restrict__ w2, unsigned short* __restrict__ w2p,
    const float* __restrict__ w1, unsigned short* __restrict__ w1p)
{
    int i = blockIdx.x;
    if (i >= 2048) {
        int bid2 = i - 2048;
        if (bid2 < 128) {
            // w2: 512 cols x 16 kc x 4 kg fragments
            int u  = bid2 * 256 + threadIdx.x;     // kg fastest, then kc, then col
            int kg = u & 3, kc = (u >> 2) & 15, c = u >> 6;
            const float* src = w2 + (size_t)c * 512 + kc * 32 + kg * 8;
            unsigned short fr[8];
#pragma unroll
            for (int e = 0; e < 8; ++e) fr[e] = f2bf(src[e]);
            *(u16x8*)(w2p + ((((size_t)kc * 512 + c) * 4 + kg) << 3)) = *(u16x8*)fr;
        } else {
            // w1: 512 cols x 2 ks x 4 kg fragments, K padded 40->64 with zeros
            int u  = (bid2 - 128) * 256 + threadIdx.x;   // 4096 total
            int kg = u & 3, ks = (u >> 2) & 1, c = u >> 3;
            int kbase = ks * 32 + kg * 8;
            unsigned short fr[8];
#pragma unroll
            for (int e = 0; e < 8; ++e) {
                int k = kbase + e;
                fr[e] = (k < 40) ? f2bf(w1[(size_t)c * 40 + k]) : (unsigned short)0;
            }
            *(u16x8*)(w1p + ((((size_t)ks * 512 + c) * 4 + kg) << 3)) = *(u16x8*)fr;
        }
        return;
    }

    int l = (i & 7) + ((i >> 10) << 3);
    int b = ((i & 1023) >> 3) * 256 + threadIdx.x;

    const float4 x0 = *(const float4*)(x + (size_t)b * DD);
    const float4 x1 = *(const float4*)(x + (size_t)b * DD + 4);
    float xs[8] = {x0.x, x0.y, x0.z, x0.w, x1.x, x1.y, x1.z, x1.w};

    float Kl = Karr[l];
    const f32x2* Tl = (const f32x2*)(T + ((size_t)l * TBL) * 2);

    uint32_t idx9[9];
    float    w9[9];
    enc_idx(xs, Kl, idx9, w9);

    f32x2 t0, t1, t2, t3, t4, t5, t6, t7, t8;
#define GL(n) asm volatile("global_load_dwordx2 %0, %1, off" \
                           : "=v"(t##n) : "v"(Tl + idx9[n]));
    GL(0) GL(1) GL(2) GL(3) GL(4) GL(5) GL(6) GL(7) GL(8)
#undef GL
    asm volatile("s_waitcnt vmcnt(0)"
        : "+v"(t0), "+v"(t1), "+v"(t2), "+v"(t3), "+v"(t4),
          "+v"(t5), "+v"(t6), "+v"(t7), "+v"(t8));
    __builtin_amdgcn_sched_barrier(0);

    float f0, f1;
    f0 = t0[0] * w9[0];  f1 = t0[1] * w9[0];
    f0 = fmaf(t1[0], w9[1], f0); f1 = fmaf(t1[1], w9[1], f1);
    f0 = fmaf(t2[0], w9[2], f0); f1 = fmaf(t2[1], w9[2], f1);
    f0 = fmaf(t3[0], w9[3], f0); f1 = fmaf(t3[1], w9[3], f1);
    f0 = fmaf(t4[0], w9[4], f0); f1 = fmaf(t4[1], w9[4], f1);
    f0 = fmaf(t5[0], w9[5], f0); f1 = fmaf(t5[1], w9[5], f1);
    f0 = fmaf(t6[0], w9[6], f0); f1 = fmaf(t6[1], w9[6], f1);
    f0 = fmaf(t7[0], w9[7], f0); f1 = fmaf(t7[1], w9[7], f1);
    f0 = fmaf(t8[0], w9[8], f0); f1 = fmaf(t8[1], w9[8], f1);
    f0 /= Kl;
    f1 /= Kl;

    h0T[(size_t)(l * 2 + 0) * BB + b] = f2bf(f0);
    h0T[(size_t)(l * 2 + 1) * BB + b] = f2bf(f1);
}

// ---------------- fused MLP: stages h0T+x itself, writes out directly ----------------
// 256 blocks x 512 threads (8 waves 2x4), h1 tile in 128 KB LDS (1 block/CU).
// B-operands from fragment-packed w1p/w2p (contiguous 1KB wave-loads, L2-hot).
// Phase-2: 16 unrolled steps, named dbuf regs, loads(k+1) before MFMAs(k);
// first two B-fragment sets prefetched before the phase1->2 barrier.
// Epilogue: per-wn head partials -> LDS -> cross-wn sum -> out.
__global__ __launch_bounds__(512, 2) void k_fused(
    const unsigned short* __restrict__ h0T, const float* __restrict__ x,
    const unsigned short* __restrict__ w1p, const unsigned short* __restrict__ w2p,
    const float* __restrict__ b1, const float* __restrict__ b2,
    const float* __restrict__ aw, const float* __restrict__ ab,
    const float* __restrict__ vw, const float* __restrict__ vb,
    float* __restrict__ out)
{
    __shared__ unsigned short h1s[128 * 512];   // 128 KiB, swizzled [row][k]
    __shared__ unsigned short h0s[128 * 64];    // 16 KiB,  swizzled [row][k]; reused as spart

    const int tid  = threadIdx.x;
    const int wid  = tid >> 6;
    const int lane = tid & 63;
    const int wm = wid >> 2, wn = wid & 3;
    const int lr = lane & 15;
    const int kg = lane >> 4;
    const int b0 = blockIdx.x * 128;

    // ---- stage h0 tile straight from h0T planes + x (transpose via ds_writes) ----
    {
        // 32 planes x 128 samples: thread t covers plane t>>4, samples (t&15)*8..+8
        int p = tid >> 4, c = tid & 15;
        u16x8 v = *(const u16x8*)(h0T + (size_t)p * BB + b0 + c * 8);
#pragma unroll
        for (int e = 0; e < 8; ++e) {
            int row = c * 8 + e;
            int byte = ((row << 7) + (8 + p) * 2) ^ ((row & 7) << 4);
            *(unsigned short*)((char*)h0s + byte) = v[e];
        }
        if (tid < 128) {            // x rows -> cols 0..7 (one b128 per row)
            int row = tid;
            const float4 x0 = *(const float4*)(x + (size_t)(b0 + row) * 8);
            const float4 x1 = *(const float4*)(x + (size_t)(b0 + row) * 8 + 4);
            unsigned short xv[8] = {
                f2bf(x0.x), f2bf(x0.y), f2bf(x0.z), f2bf(x0.w),
                f2bf(x1.x), f2bf(x1.y), f2bf(x1.z), f2bf(x1.w)};
            *(u16x8*)((char*)h0s + ((row << 7) ^ ((row & 7) << 4))) = *(u16x8*)xv;
        } else {                    // zero-pad cols 40..63 (3 x 16B per row)
            int t2 = tid - 128;     // 0..383
            int row = t2 / 3, seg = t2 - row * 3;
            int byte = ((row << 7) + 80 + seg * 16) ^ ((row & 7) << 4);
            u16x8 z = {0, 0, 0, 0, 0, 0, 0, 0};
            *(u16x8*)((char*)h0s + byte) = z;
        }
    }
    __syncthreads();

    f32x4 acc[4][8];
#pragma unroll
    for (int m = 0; m < 4; ++m)
#pragma unroll
        for (int n = 0; n < 8; ++n) acc[m][n] = (f32x4){0.f, 0.f, 0.f, 0.f};

    // ---- phase 1: h1 = relu(h0 @ w1^T + b1), K=64 ----
#pragma unroll
    for (int ks = 0; ks < 2; ++ks) {
        int kbyte = ks * 64 + kg * 16;
        short8 af[4];
#pragma unroll
        for (int m = 0; m < 4; ++m) {
            int row = wm * 64 + m * 16 + lr;
            int a = ((row << 7) + kbyte) ^ ((row & 7) << 4);
            af[m] = *(const short8*)((const char*)h0s + a);
        }
        short8 bfr[8];
#pragma unroll
        for (int n = 0; n < 8; ++n) {
            int col = wn * 128 + n * 16 + lr;
            bfr[n] = *(const short8*)(w1p + ((((size_t)ks * 512 + col) * 4 + kg) << 3));
        }
#pragma unroll
        for (int m = 0; m < 4; ++m)
#pragma unroll
            for (int n = 0; n < 8; ++n)
                acc[m][n] = __builtin_amdgcn_mfma_f32_16x16x32_bf16(
                    af[m], bfr[n], acc[m][n], 0, 0, 0);
    }

    short8 aX[4], bX[8], aY[4], bY[8];

#define LDA(dst, kc)                                                            \
    _Pragma("unroll")                                                           \
    for (int m = 0; m < 4; ++m) {                                               \
        int row = wm * 64 + m * 16 + lr;                                        \
        int a = (((row << 10) + (kc) * 64 + kg * 16)) ^ ((row & 7) << 4);       \
        dst[m] = *(const short8*)((const char*)h1s + a);                        \
    }
#define LDB(dst, kc)                                                            \
    _Pragma("unroll")                                                           \
    for (int n = 0; n < 8; ++n) {                                               \
        int col = wn * 128 + n * 16 + lr;                                       \
        dst[n] = *(const short8*)(w2p + ((((size_t)(kc) * 512 + col) * 4 + kg) << 3)); \
    }
#define MM(aa, bb)                                                              \
    __builtin_amdgcn_sched_barrier(0);                                          \
    __builtin_amdgcn_s_setprio(1);                                              \
    _Pragma("unroll")                                                           \
    for (int m = 0; m < 4; ++m)                                                 \
        _Pragma("unroll")                                                       \
        for (int n = 0; n < 8; ++n)                                             \
            acc[m][n] = __builtin_amdgcn_mfma_f32_16x16x32_bf16(                \
                aa[m], bb[n], acc[m][n], 0, 0, 0);                              \
    __builtin_amdgcn_s_setprio(0);

    // bias + relu -> bf16 -> swizzled LDS h1 tile (row stride 1024 B);
    // prefetch phase-2's first two B-fragment sets under the writes+barrier
    // (w2p loads have no LDS dependency).
    LDB(bX, 0)
    LDB(bY, 1)
#pragma unroll
    for (int n = 0; n < 8; ++n) {
        int col = wn * 128 + n * 16 + lr;
        float b1v = b1[col];
#pragma unroll
        for (int m = 0; m < 4; ++m) {
#pragma unroll
            for (int r = 0; r < 4; ++r) {
                int row = wm * 64 + m * 16 + kg * 4 + r;
                int byte = ((row << 10) + col * 2) ^ ((row & 7) << 4);
                *(unsigned short*)((char*)h1s + byte) =
                    f2bf(fmaxf(acc[m][n][r] + b1v, 0.f));
            }
        }
    }
    __syncthreads();    // h1 tile complete; h0s no longer read

    // ---- phase 2: K=512, A from LDS, B from packed w2p, 1-deep named dbuf ----
#pragma unroll
    for (int m = 0; m < 4; ++m)
#pragma unroll
        for (int n = 0; n < 8; ++n) acc[m][n] = (f32x4){0.f, 0.f, 0.f, 0.f};

    LDA(aX, 0)
    LDA(aY, 1)              MM(aX, bX)
    LDA(aX, 2)  LDB(bX, 2)  MM(aY, bY)
    LDA(aY, 3)  LDB(bY, 3)  MM(aX, bX)
    LDA(aX, 4)  LDB(bX, 4)  MM(aY, bY)
    LDA(aY, 5)  LDB(bY, 5)  MM(aX, bX)
    LDA(aX, 6)  LDB(bX, 6)  MM(aY, bY)
    LDA(aY, 7)  LDB(bY, 7)  MM(aX, bX)
    LDA(aX, 8)  LDB(bX, 8)  MM(aY, bY)
    LDA(aY, 9)  LDB(bY, 9)  MM(aX, bX)
    LDA(aX, 10) LDB(bX, 10) MM(aY, bY)
    LDA(aY, 11) LDB(bY, 11) MM(aX, bX)
    LDA(aX, 12) LDB(bX, 12) MM(aY, bY)
    LDA(aY, 13) LDB(bY, 13) MM(aX, bX)
    LDA(aX, 14) LDB(bX, 14) MM(aY, bY)
    LDA(aY, 15) LDB(bY, 15) MM(aX, bX)
    MM(aY, bY)
#undef LDA
#undef LDB
#undef MM

    // ---- epilogue: bias+relu (fp32), head dots, in-block cross-wn reduction ----
#pragma unroll
    for (int n = 0; n < 8; ++n) {
        int col = wn * 128 + n * 16 + lr;
        float b2v = b2[col];
#pragma unroll
        for (int m = 0; m < 4; ++m)
#pragma unroll
            for (int r = 0; r < 4; ++r)
                acc[m][n][r] = fmaxf(acc[m][n][r] + b2v, 0.f);
    }

    float hwv[5][8];
#pragma unroll
    for (int n = 0; n < 8; ++n) {
        int col = wn * 128 + n * 16 + lr;
        hwv[0][n] = aw[col];
        hwv[1][n] = aw[512 + col];
        hwv[2][n] = aw[1024 + col];
        hwv[3][n] = aw[1536 + col];
        hwv[4][n] = vw[col];
    }
    float* spart = (float*)h0s;               // [wn][hm][row] = 4*5*128 f32 = 10 KB
#pragma unroll
    for (int hm = 0; hm < 5; ++hm) {
        f32x4 p[4];
#pragma unroll
        for (int m = 0; m < 4; ++m) {
            p[m] = acc[m][0] * hwv[hm][0];
#pragma unroll
            for (int n = 1; n < 8; ++n) p[m] += acc[m][n] * hwv[hm][n];
        }
#pragma unroll
        for (int d = 1; d < 16; d <<= 1)
#pragma unroll
            for (int m = 0; m < 4; ++m)
#pragma unroll
                for (int r = 0; r < 4; ++r)
                    p[m][r] += __shfl_xor(p[m][r], d);
        if (lr == 0) {
#pragma unroll
            for (int m = 0; m < 4; ++m)
#pragma unroll
                for (int r = 0; r < 4; ++r)
                    spart[(wn * 5 + hm) * 128 + wm * 64 + m * 16 + kg * 4 + r] = p[m][r];
        }
    }
    __syncthreads();

    if (tid < 128) {
        int b = b0 + tid;
        float s[5];
#pragma unroll
        for (int hm = 0; hm < 5; ++hm) {
            float v = spart[(0 * 5 + hm) * 128 + tid] + spart[(1 * 5 + hm) * 128 + tid]
                    + spart[(2 * 5 + hm) * 128 + tid] + spart[(3 * 5 + hm) * 128 + tid];
            s[hm] = v;
        }
        float4 act = make_float4(s[0] + ab[0], s[1] + ab[1], s[2] + ab[2], s[3] + ab[3]);
        *(float4*)(out + (size_t)b * 4) = act;
        out[(size_t)BB * 4 + b] = s[4] + vb[0];
    }
}

extern "C" void kernel_launch(void* const* d_in, const int* in_sizes, int n_in,
                              void* d_out, int out_size, void* d_ws, size_t ws_size,
                              hipStream_t stream)
{
    const float* x    = (const float*)d_in[0];
    const float* T    = (const float*)d_in[1];
    const float* K    = (const float*)d_in[2];
    const float* l1w  = (const float*)d_in[3];
    const float* l1b  = (const float*)d_in[4];
    const float* l2w  = (const float*)d_in[5];
    const float* l2b  = (const float*)d_in[6];
    const float* actw = (const float*)d_in[7];
    const float* actb = (const float*)d_in[8];
    const float* valw = (const float*)d_in[9];
    const float* valb = (const float*)d_in[10];
    float* out = (float*)d_out;

    char* ws = (char*)d_ws;
    unsigned short* h0T = (unsigned short*)ws;                  // 32*B bf16   = 2,097,152 B
    unsigned short* w2p = (unsigned short*)(ws + 2097152);      // 512*512 bf16= 524,288 B
    unsigned short* w1p = (unsigned short*)(ws + 2621440);      // 512*64 bf16 = 65,536 B

    k_encode <<<2192, 256, 0, stream>>>(x, T, K, h0T, l2w, w2p, l1w, w1p);
    k_fused  <<<256, 512, 0, stream>>>(h0T, x, w1p, w2p, l1b, l2b,
                                       actw, actb, valw, valb, out);
}